// Round 11
// baseline (71.674 us; speedup 1.0000x reference)
//
#include <hip/hip_runtime.h>

#define T_ 1000
#define T4_ 250
#define B_ 64
#define V_ 1024
#define NEGF (-1e30f)
#define LOG2E_ 1.4426950408889634f
#define LN2_ 0.6931471805599453f
// Q3(u) ~= log2(1+u), u in [0,1]; Q3(1)=1 exact; |err| <= ~3e-3
#define P0C 1.4405f
#define P1C (-0.64178f)
#define P2C 0.20128f

__device__ __forceinline__ float ex2(float x) { return __builtin_amdgcn_exp2f(x); }
__device__ __forceinline__ float lg2(float x) { return __builtin_amdgcn_logf(x); }
__device__ __forceinline__ float rlane(float x, int l) {
    return __int_as_float(__builtin_amdgcn_readlane(__float_as_int(x), l));
}
#define FENCE_ __builtin_amdgcn_sched_barrier(0)

// In-wave target setup (B_ == 64 == wave): lane l gets tgt[l] of sample b, plus L.
__device__ __forceinline__ void load_tgt(const int* __restrict__ targets,
                                         const int* __restrict__ tlen,
                                         int b, int lane, int& tg, int& L) {
    int tl = tlen[lane];
    L = __shfl(tl, b);
    int v = (lane < b) ? tl : 0;
    for (int off = 32; off; off >>= 1) v += __shfl_xor(v, off);  // offset_b (uniform)
    tg = (lane < L) ? targets[v + lane] : 0;
}

// Scatter-gather: em4f[((b*250+t4)*64+i)*4+tq] = log2e * lp[t, b, i<63 ? tgt[i] : BLANK]
// (L<=63: lane 63's label slot carries the blank column.) Skips t >= ilen[b].
__global__ __launch_bounds__(256) void gather_k(const float* __restrict__ lp,
                                                const int* __restrict__ targets,
                                                const int* __restrict__ tlen,
                                                const int* __restrict__ ilen,
                                                float* __restrict__ em4f) {
    int t4 = blockIdx.x % T4_;
    int b = blockIdx.x / T4_;
    int tq = threadIdx.x >> 6;
    int i = threadIdx.x & 63;
    int tg, L;
    load_tgt(targets, tlen, b, i, tg, L);
    int t = t4 * 4 + tq;
    if (t >= ilen[b]) return;                 // wave-uniform (tq per wave)
    int col = (i == 63) ? 0 : tg;
    em4f[(((size_t)b * T4_ + t4) * 64 + i) * 4 + tq] =
        lp[((size_t)t << 16) + (b << 10) + col] * LOG2E_;
}

// Fused fwd/bwd CTC on compact em4. Blocks 0..63: alpha forward to t=M (M=Te/2).
// Blocks 64..127: beta backward from Te down to M+1. Junction -> aw[b][4][64].
__global__ __launch_bounds__(64) void ctc_fb_k(const float4* __restrict__ e44,
                                               const int* __restrict__ targets,
                                               const int* __restrict__ tlen,
                                               const int* __restrict__ ilen,
                                               float* __restrict__ aw) {
    int blk = blockIdx.x, lane = threadIdx.x;
    bool isFwd = blk < B_;
    int b = isFwd ? blk : blk - B_;
    int tg, L;
    load_tgt(targets, tlen, b, lane, tg, L);
    int Tin = ilen[b], Te = Tin - 1;
    int M = Te >> 1;
    int tgp = __shfl_up(tg, 1);
    bool skip1 = (lane >= 1) && (tg != 0) && (tg != tgp);
    const float4* e44b = e44 + (size_t)b * (T4_ * 64) + lane;  // [group*64]
    float* awb = aw + b * 256;

    if (isFwd) {
        bool is16 = (lane == 16), is32 = (lane == 32), is48 = (lane == 48);
        float a0 = NEGF, a1 = NEGF;
        int Gc = M >> 2; if (Gc < 0) Gc = 0;
        auto ldG = [&](int g, float4& S) {
            int gm = g < Gc ? g : Gc;
            S = e44b[(size_t)gm * 64];
        };
        auto shr1 = [&](float x) -> float {    // lane i <- x[i-1]; lane 0 <- NEGF
            float v15 = rlane(x, 15), v31 = rlane(x, 31), v47 = rlane(x, 47);
            float bval = is16 ? v15 : (is32 ? v31 : (is48 ? v47 : NEGF));
            return __int_as_float(__builtin_amdgcn_update_dpp(
                __float_as_int(bval), __float_as_int(x), 0x111, 0xF, 0xF, false));
        };
        auto step = [&](float xb, float xe) {
            float p1m = shr1(a1);
            float d0 = a0 - p1m;
            float m0 = fmaxf(a0, p1m);
            float u = ex2(-fabsf(d0));
            float h = fmaf(u, P2C, P1C);
            h = fmaf(u, h, P0C);
            float U = fmaf(u, h, m0);          // lae(a0, p1m)
            float na0 = U + xb;
            float w = skip1 ? U : a0;
            float d1 = a1 - w;
            float m1 = fmaxf(a1, w);
            float v = ex2(-fabsf(d1));
            float h1 = fmaf(v, P2C, P1C);
            h1 = fmaf(v, h1, P0C);
            float na1 = fmaf(v, h1, m1 + xe);
            a0 = na0; a1 = na1;
        };
#define STEPF(C) do { float xb_ = rlane((C), 63); step(xb_, (C)); } while (0)
        if (M >= 35) {
            float4 S0, S1, S2, S3, S4, S5, S6, S7;
            ldG(0, S0); ldG(1, S1); ldG(2, S2); ldG(3, S3);
            ldG(4, S4); ldG(5, S5); ldG(6, S6); ldG(7, S7);
            FENCE_;
            a0 = (lane == 0) ? rlane(S0.x, 63) : NEGF;
            a1 = (lane == 0 && L > 0) ? S0.x : NEGF;
            STEPF(S0.y); STEPF(S0.z); STEPF(S0.w);
            ldG(8, S0);
            FENCE_;
#define SUBF_F(S, G) do { STEPF(S.x); STEPF(S.y); STEPF(S.z); STEPF(S.w); \
                          ldG((G) + 8, S); FENCE_; } while (0)
            SUBF_F(S1, 1); SUBF_F(S2, 2); SUBF_F(S3, 3); SUBF_F(S4, 4);
            SUBF_F(S5, 5); SUBF_F(S6, 6); SUBF_F(S7, 7);
            int c = 1;
            for (; 32 * c + 31 <= M; ++c) {
                int g0 = 8 * c;
                SUBF_F(S0, g0 + 0); SUBF_F(S1, g0 + 1); SUBF_F(S2, g0 + 2); SUBF_F(S3, g0 + 3);
                SUBF_F(S4, g0 + 4); SUBF_F(S5, g0 + 5); SUBF_F(S6, g0 + 6); SUBF_F(S7, g0 + 7);
            }
#undef SUBF_F
            int tb = 32 * c;
#define SUBT_F(S, T0) do { if ((T0) + 0 <= M) STEPF(S.x); if ((T0) + 1 <= M) STEPF(S.y); \
                           if ((T0) + 2 <= M) STEPF(S.z); if ((T0) + 3 <= M) STEPF(S.w); } while (0)
            SUBT_F(S0, tb + 0);  SUBT_F(S1, tb + 4);  SUBT_F(S2, tb + 8);  SUBT_F(S3, tb + 12);
            SUBT_F(S4, tb + 16); SUBT_F(S5, tb + 20); SUBT_F(S6, tb + 24); SUBT_F(S7, tb + 28);
#undef SUBT_F
        } else if (Tin >= 1) {
            const float* emf0 = (const float*)e44b;
            float e = emf0[0];
            a0 = (lane == 0) ? rlane(e, 63) : NEGF;
            a1 = (lane == 0 && L > 0) ? e : NEGF;
            for (int t = 1; t <= M; ++t) {
                float xe = ((const float*)(e44b + (size_t)(t >> 2) * 64))[t & 3];
                STEPF(xe);
            }
        }
#undef STEPF
        awb[lane] = a0;
        awb[64 + lane] = a1;
    } else {
        // ---------------- backward ----------------
        bool is15 = (lane == 15), is31 = (lane == 31), is47 = (lane == 47);
        int K = Te - M;                        // steps, consuming t = Te .. M+1
        float B0 = (lane == L) ? 0.0f : NEGF;
        float B1 = (L > 0 && lane == L - 1) ? 0.0f : NEGF;
        auto shl1 = [&](float x) -> float {    // lane i <- x[i+1]; lane 63 <- NEGF
            float v16 = rlane(x, 16), v32 = rlane(x, 32), v48 = rlane(x, 48);
            float bval = is15 ? v16 : (is31 ? v32 : (is47 ? v48 : NEGF));
            return __int_as_float(__builtin_amdgcn_update_dpp(
                __float_as_int(bval), __float_as_int(x), 0x101, 0xF, 0xF, false));
        };
        auto stepb = [&](float xb, float xe) {
            float z = B1 + xe;
            float t0v = B0 + xb;
            float d0 = t0v - z;
            float m0 = fmaxf(t0v, z);
            float u = ex2(-fabsf(d0));
            float h = fmaf(u, P2C, P1C);
            h = fmaf(u, h, P0C);
            float B0n = fmaf(u, h, m0);        // lae2(t0v, z)
            float y = skip1 ? B0n : t0v;
            float arg = shl1(y);
            float d1 = z - arg;
            float m1 = fmaxf(z, arg);
            float v = ex2(-fabsf(d1));
            float h1 = fmaf(v, P2C, P1C);
            h1 = fmaf(v, h1, P0C);
            float B1n = fmaf(v, h1, m1);       // lae2(z, arg)
            B0 = B0n; B1 = B1n;
        };
#define STEPB(C) do { float xb_ = rlane((C), 63); stepb(xb_, (C)); } while (0)
        if (K >= 40) {
            int gh = Te >> 2, rP = Te & 3;
            int KR = K - rP - 1;               // steps after prologue (>= 36)
            auto ldGb = [&](int q, float4& S) {
                int g = gh - 1 - q; if (g < 0) g = 0;
                S = e44b[(size_t)g * 64];
            };
            float4 P = e44b[(size_t)gh * 64];
            float4 S0, S1, S2, S3, S4, S5, S6, S7;
            ldGb(0, S0); ldGb(1, S1); ldGb(2, S2); ldGb(3, S3);
            ldGb(4, S4); ldGb(5, S5); ldGb(6, S6); ldGb(7, S7);
            FENCE_;
            if (rP == 3)      { STEPB(P.w); STEPB(P.z); STEPB(P.y); STEPB(P.x); }
            else if (rP == 2) { STEPB(P.z); STEPB(P.y); STEPB(P.x); }
            else if (rP == 1) { STEPB(P.y); STEPB(P.x); }
            else              { STEPB(P.x); }
#define SUBF_B(S, Q) do { STEPB(S.w); STEPB(S.z); STEPB(S.y); STEPB(S.x); \
                          ldGb((Q) + 8, S); FENCE_; } while (0)
            SUBF_B(S0, 0); SUBF_B(S1, 1); SUBF_B(S2, 2); SUBF_B(S3, 3);
            SUBF_B(S4, 4); SUBF_B(S5, 5); SUBF_B(S6, 6); SUBF_B(S7, 7);
            int c = 1;
            for (; 32 * c + 32 <= KR; ++c) {
                int q0 = 8 * c;
                SUBF_B(S0, q0 + 0); SUBF_B(S1, q0 + 1); SUBF_B(S2, q0 + 2); SUBF_B(S3, q0 + 3);
                SUBF_B(S4, q0 + 4); SUBF_B(S5, q0 + 5); SUBF_B(S6, q0 + 6); SUBF_B(S7, q0 + 7);
            }
#undef SUBF_B
            int sb = 32 * c;                   // next step index - 1 (steps are 1-based)
#define SUBT_B(S, S0i) do { if ((S0i) + 0 <= KR) STEPB(S.w); if ((S0i) + 1 <= KR) STEPB(S.z); \
                            if ((S0i) + 2 <= KR) STEPB(S.y); if ((S0i) + 3 <= KR) STEPB(S.x); } while (0)
            SUBT_B(S0, sb + 1);  SUBT_B(S1, sb + 5);  SUBT_B(S2, sb + 9);  SUBT_B(S3, sb + 13);
            SUBT_B(S4, sb + 17); SUBT_B(S5, sb + 21); SUBT_B(S6, sb + 25); SUBT_B(S7, sb + 29);
#undef SUBT_B
        } else {
            for (int k = 0; k < K; ++k) {
                int t = Te - k;
                float xe = ((const float*)(e44b + (size_t)(t >> 2) * 64))[t & 3];
                STEPB(xe);
            }
        }
#undef STEPB
        awb[128 + lane] = B0;
        awb[192 + lane] = B1;
    }
}

// Merged combine (junction logsumexp over 128 states) + batch/group finalize.
__global__ __launch_bounds__(256) void tail_k(const float* __restrict__ aw,
                                              const int* __restrict__ tlen,
                                              const int* __restrict__ ilen,
                                              const int* __restrict__ gid,
                                              float* __restrict__ out) {
    __shared__ float lossS[B_];
    int tid = threadIdx.x, w = tid >> 6, lane = tid & 63;
    for (int j = 0; j < 16; ++j) {
        int b = w * 16 + j;
        const float* awb = aw + b * 256;
        float s0 = awb[lane] + awb[128 + lane];
        float s1 = awb[64 + lane] + awb[192 + lane];
        float m = fmaxf(s0, s1);
        for (int off = 32; off; off >>= 1) m = fmaxf(m, __shfl_xor(m, off));
        float sum = ex2(s0 - m) + ex2(s1 - m);
        for (int off = 32; off; off >>= 1) sum += __shfl_xor(sum, off);
        if (lane == 0) {
            int L = tlen[b];
            float fin = lg2(sum) + m;          // log2 domain
            if (ilen[b] <= 0) fin = NEGF;
            float loss = (L > 0) ? -fin * LN2_ : 0.0f;
            if (!(loss < 1e29f)) loss = 0.0f;  // zero_infinity (NaN-safe)
            lossS[b] = loss;
        }
    }
    __syncthreads();
    if (w == 0) {
        float l = lossS[lane];
        int g = gid[lane];
        float s = l;
        float s0 = (g == 0) ? l : 0.0f, c0 = (g == 0) ? 1.0f : 0.0f;
        float s1 = (g == 1) ? l : 0.0f, c1 = (g == 1) ? 1.0f : 0.0f;
        for (int off = 32; off; off >>= 1) {
            s  += __shfl_xor(s, off);
            s0 += __shfl_xor(s0, off);
            c0 += __shfl_xor(c0, off);
            s1 += __shfl_xor(s1, off);
            c1 += __shfl_xor(c1, off);
        }
        if (lane == 0) {
            float base = s * (1.0f / B_);
            float m0 = s0 / fmaxf(c0, 1.0f);
            float m1 = s1 / fmaxf(c1, 1.0f);
            float mean = 0.5f * (m0 + m1);
            float var = (m0 - mean) * (m0 - mean) + (m1 - mean) * (m1 - mean); // ddof=1
            out[0] = base + 0.5f * var;
            out[1] = base;
            out[2] = var;
        }
    }
}

// Fallback when ws too small: fully serial per-sample forward straight from lp.
__global__ __launch_bounds__(64) void ctc_rec_direct_k(const float* __restrict__ lp,
                                                       const int* __restrict__ targets,
                                                       const int* __restrict__ tlen,
                                                       const int* __restrict__ ilen,
                                                       float* __restrict__ losses) {
    int b = blockIdx.x, lane = threadIdx.x;
    int tg, L;
    load_tgt(targets, tlen, b, lane, tg, L);
    int Tin = ilen[b], Te = Tin - 1;
    int tgp = __shfl_up(tg, 1);
    bool skip1 = (lane >= 1) && (tg != 0) && (tg != tgp);
    bool is16 = (lane == 16), is32 = (lane == 32), is48 = (lane == 48);
    int col = (lane == 63) ? 0 : tg;
    int idx = (b << 10) + col;
    float a0 = NEGF, a1 = NEGF;
    auto shr1 = [&](float x) -> float {
        float v15 = rlane(x, 15), v31 = rlane(x, 31), v47 = rlane(x, 47);
        float bval = is16 ? v15 : (is32 ? v31 : (is48 ? v47 : NEGF));
        return __int_as_float(__builtin_amdgcn_update_dpp(
            __float_as_int(bval), __float_as_int(x), 0x111, 0xF, 0xF, false));
    };
    auto step = [&](float xb, float xe) {
        float p1m = shr1(a1);
        float d0 = a0 - p1m;
        float m0 = fmaxf(a0, p1m);
        float u = ex2(-fabsf(d0));
        float h = fmaf(u, P2C, P1C);
        h = fmaf(u, h, P0C);
        float U = fmaf(u, h, m0);
        float na0 = U + xb;
        float w = skip1 ? U : a0;
        float d1 = a1 - w;
        float m1 = fmaxf(a1, w);
        float v = ex2(-fabsf(d1));
        float h1 = fmaf(v, P2C, P1C);
        h1 = fmaf(v, h1, P0C);
        float na1 = fmaf(v, h1, m1 + xe);
        a0 = na0; a1 = na1;
    };
    if (Tin >= 1) {
        float e = lp[idx] * LOG2E_;
        a0 = (lane == 0) ? rlane(e, 63) : NEGF;
        a1 = (lane == 0 && L > 0) ? e : NEGF;
        for (int t = 1; t <= Te; ++t) {
            float xe = (lp + ((size_t)t << 16))[idx] * LOG2E_;
            step(rlane(xe, 63), xe);
        }
    }
    int lidx = (L > 0) ? (L - 1) : 0;
    float aPrev = __shfl(a1, lidx);
    float aLast = __shfl(a0, (L < 63) ? L : 63);
    float x = aLast, y = (L > 0) ? aPrev : NEGF;
    float m = fmaxf(x, y), d = fminf(x, y) - m;
    float fin = m + lg2(1.0f + ex2(d));
    if (Tin <= 0) fin = NEGF;
    if (lane == 0) {
        float loss = (L > 0) ? -fin * LN2_ : 0.0f;
        if (!(loss < 1e29f)) loss = 0.0f;
        losses[b] = loss;
    }
}

__global__ __launch_bounds__(64) void finalize_k(const float* __restrict__ losses,
                                                 const int* __restrict__ gid,
                                                 float* __restrict__ out) {
    int lane = threadIdx.x;
    float l = losses[lane];
    int g = gid[lane];
    float s = l;
    float s0 = (g == 0) ? l : 0.0f, c0 = (g == 0) ? 1.0f : 0.0f;
    float s1 = (g == 1) ? l : 0.0f, c1 = (g == 1) ? 1.0f : 0.0f;
    for (int off = 32; off; off >>= 1) {
        s  += __shfl_xor(s, off);
        s0 += __shfl_xor(s0, off);
        c0 += __shfl_xor(c0, off);
        s1 += __shfl_xor(s1, off);
        c1 += __shfl_xor(c1, off);
    }
    if (lane == 0) {
        float base = s * (1.0f / B_);
        float m0 = s0 / fmaxf(c0, 1.0f);
        float m1 = s1 / fmaxf(c1, 1.0f);
        float mean = 0.5f * (m0 + m1);
        float var = (m0 - mean) * (m0 - mean) + (m1 - mean) * (m1 - mean);
        out[0] = base + 0.5f * var;
        out[1] = base;
        out[2] = var;
    }
}

extern "C" void kernel_launch(void* const* d_in, const int* in_sizes, int n_in,
                              void* d_out, int out_size, void* d_ws, size_t ws_size,
                              hipStream_t stream) {
    const float* lp = (const float*)d_in[0];
    const int* targets = (const int*)d_in[1];
    const int* ilen = (const int*)d_in[2];
    const int* tlen = (const int*)d_in[3];
    const int* gid = (const int*)d_in[4];
    float* out = (float*)d_out;

    char* ws = (char*)d_ws;
    float* losses = (float*)ws;                       // 256 B (fallback only)
    float* aw = (float*)(ws + 1024);                  // 64*256*4 = 64 KB
    float* em4f = (float*)(ws + 131072);              // 64*250*64*4 floats = 16.38 MB
    size_t need = 131072 + (size_t)B_ * T4_ * 64 * 4 * sizeof(float);

    if (ws_size >= need) {
        gather_k<<<B_ * T4_, 256, 0, stream>>>(lp, targets, tlen, ilen, em4f);
        ctc_fb_k<<<2 * B_, 64, 0, stream>>>((const float4*)em4f, targets, tlen, ilen, aw);
        tail_k<<<1, 256, 0, stream>>>(aw, tlen, ilen, gid, out);
    } else {
        ctc_rec_direct_k<<<B_, 64, 0, stream>>>(lp, targets, tlen, ilen, losses);
        finalize_k<<<1, 64, 0, stream>>>(losses, gid, out);
    }
}